// Round 6
// baseline (385.376 us; speedup 1.0000x reference)
//
#include <hip/hip_runtime.h>
#include <math.h>

#define HH 12
#define NN 1024

typedef unsigned int u32;
typedef unsigned short u16;
typedef __attribute__((ext_vector_type(8))) short bf16x8;
typedef __attribute__((ext_vector_type(4))) float f32x4;
typedef __attribute__((ext_vector_type(4))) unsigned short u16x4;

#define QSCALE 0.18033688f   // 0.125 * log2(e): folded scale + base-2 softmax

__device__ __forceinline__ u16 bf16_rtn(float f) {
    u32 u = __builtin_bit_cast(u32, f);
    return (u16)((u + 0x7FFFu + ((u >> 16) & 1u)) >> 16);
}
__device__ __forceinline__ float bf16_up(u16 h) {
    u32 u = ((u32)h) << 16;
    return __builtin_bit_cast(float, u);
}
// async global->LDS, 16B per lane, dest = uniform base + lane*16
__device__ __forceinline__ void gld_lds16(const void* g, void* l) {
    __builtin_amdgcn_global_load_lds(
        (const __attribute__((address_space(1))) u32*)(unsigned long long)g,
        (__attribute__((address_space(3))) u32*)(u32)(unsigned long long)l,
        16, 0, 0);
}

// ---------------------------------------------------------------------------
// One-time f32 -> (hi,lo) bf16 split, rtn both planes (err ~2^-18)
// ---------------------------------------------------------------------------
__global__ __launch_bounds__(256) void presplit(const float* __restrict__ in,
                                                u16* __restrict__ hi, u16* __restrict__ lo,
                                                int n4) {
    int i = blockIdx.x * 256 + threadIdx.x;
    if (i >= n4) return;
    float4 v = ((const float4*)in)[i];
    float f[4] = {v.x, v.y, v.z, v.w};
    u16x4 h, l;
#pragma unroll
    for (int j = 0; j < 4; ++j) {
        u16 hh = bf16_rtn(f[j]);
        h[j] = hh;
        l[j] = bf16_rtn(f[j] - bf16_up(hh));
    }
    ((u16x4*)hi)[i] = h;
    ((u16x4*)lo)[i] = l;
}

// ---------------------------------------------------------------------------
// QKV GEMM: Xsplit(4096x768 bf16 hi/lo) * qkv_w^T (bf16 hi/lo).
// 128x128 tile, BK=32, 4 waves 2x2, 3-term split MFMA.
// 2-phase pipeline: double-buffered LDS, one barrier per K-step,
// all staging via global_load_lds (fully async, zero staging VALU).
// XCD-chunked swizzle (m-major within chunk).
// Epilogue: q (scaled) / k as bf16 hi/lo [bh][n][64]; v single bf16 T [bh][64][n].
// ---------------------------------------------------------------------------
__global__ __launch_bounds__(256) void gemm_qkv(const u16* __restrict__ Xh,
                                                const u16* __restrict__ Xl,
                                                const u16* __restrict__ Wh,
                                                const u16* __restrict__ Wl,
                                                u16* __restrict__ qh, u16* __restrict__ ql,
                                                u16* __restrict__ kh, u16* __restrict__ kl,
                                                u16* __restrict__ vT) {
    __shared__ __align__(16) u16 sA[2][2][8][512];   // [buf][pl][tile][lane*8]
    __shared__ __align__(16) u16 sB[2][2][8][512];

    const int tid = threadIdx.x, wave = tid >> 6, lane = tid & 63;
    const int g = lane >> 4, c = lane & 15;
    // 576 blocks = 8 XCDs x 72; m-major inside chunk -> W panel hot per XCD
    const int bid = blockIdx.x;
    const int T = (bid & 7) * 72 + (bid >> 3);
    const int m0 = (T / 18) * 128, c0 = (T % 18) * 128;
    const int wm = wave >> 1, wn = wave & 1;

    f32x4 acc[4][4];
#pragma unroll
    for (int i = 0; i < 4; ++i)
#pragma unroll
        for (int j = 0; j < 4; ++j) acc[i][j] = (f32x4)(0.f);

    auto stage = [&](int kt, int b) {
#pragma unroll
        for (int qq = 0; qq < 8; ++qq) {
            const int id2 = wave * 8 + qq;
            const int pl = (id2 >> 3) & 1;
            const int t = id2 & 7;
            if (id2 < 16) {
                const u16* src = (pl ? Xl : Xh) + (size_t)(m0 + t * 16 + c) * 768 + kt * 32 + g * 8;
                gld_lds16(src, &sA[b][pl][t][0]);
            } else {
                const u16* src = (pl ? Wl : Wh) + (size_t)(c0 + t * 16 + c) * 768 + kt * 32 + g * 8;
                gld_lds16(src, &sB[b][pl][t][0]);
            }
        }
    };

    stage(0, 0);
    for (int kt = 0; kt < 24; ++kt) {
        const int b = kt & 1;
        __syncthreads();              // drains stage(kt) + prev frag reads
        if (kt < 23) stage(kt + 1, b ^ 1);   // async into other buffer, overlaps MFMAs

        bf16x8 Ah[4], Al[4], Bh[4], Bl[4];
#pragma unroll
        for (int i = 0; i < 4; ++i) {
            Ah[i] = *(const bf16x8*)&sA[b][0][wm * 4 + i][lane * 8];
            Al[i] = *(const bf16x8*)&sA[b][1][wm * 4 + i][lane * 8];
            Bh[i] = *(const bf16x8*)&sB[b][0][wn * 4 + i][lane * 8];
            Bl[i] = *(const bf16x8*)&sB[b][1][wn * 4 + i][lane * 8];
        }
#pragma unroll
        for (int i = 0; i < 4; ++i)
#pragma unroll
            for (int j = 0; j < 4; ++j) {
                acc[i][j] = __builtin_amdgcn_mfma_f32_16x16x32_bf16(Ah[i], Bh[j], acc[i][j], 0, 0, 0);
                acc[i][j] = __builtin_amdgcn_mfma_f32_16x16x32_bf16(Ah[i], Bl[j], acc[i][j], 0, 0, 0);
                acc[i][j] = __builtin_amdgcn_mfma_f32_16x16x32_bf16(Al[i], Bh[j], acc[i][j], 0, 0, 0);
            }
    }

    // Epilogue: D-frag row = g*4+r, col = c (HW-verified)
    const int b = m0 >> 10;
#pragma unroll
    for (int j = 0; j < 4; ++j) {
        const int cg = c0 + wn * 64 + j * 16;
        const int s = cg / 768;
        const int h = (cg % 768) / 64;
        const int d = (cg % 64) + c;
#pragma unroll
        for (int i = 0; i < 4; ++i) {
            const int nbase = (m0 & 1023) + wm * 64 + i * 16 + g * 4;
            if (s == 2) {
                u16x4 pk;
#pragma unroll
                for (int r = 0; r < 4; ++r) pk[r] = bf16_rtn(acc[i][j][r]);
                *(u16x4*)(vT + ((size_t)(b * HH + h) << 16) + (size_t)d * 1024 + nbase) = pk;
            } else {
                u16* dh = s ? kh : qh;
                u16* dl = s ? kl : ql;
                const float sc = s ? 1.0f : QSCALE;
#pragma unroll
                for (int r = 0; r < 4; ++r) {
                    const float vv = acc[i][j][r] * sc;
                    const u16 hh = bf16_rtn(vv);
                    const size_t a = ((size_t)(b * HH + h) * NN + nbase + r) * 64 + d;
                    dh[a] = hh;
                    dl[a] = bf16_rtn(vv - bf16_up(hh));
                }
            }
        }
    }
}

// ---------------------------------------------------------------------------
// Flash attention, MFMA + T5 setprio around MFMA clusters.
// ---------------------------------------------------------------------------
__global__ __launch_bounds__(256) void attn_mfma(const u16* __restrict__ qh_,
                                                 const u16* __restrict__ ql_,
                                                 const u16* __restrict__ kh_,
                                                 const u16* __restrict__ kl_,
                                                 const u16* __restrict__ vT,
                                                 const float* __restrict__ rel_table,
                                                 u16* __restrict__ attout) {
    __shared__ __align__(16) u16 sK[2][4][2][512];  // [pl][jn][ks]
    __shared__ __align__(16) u16 sV[4][2][512];     // [dj][ks]
    __shared__ __align__(16) u16 sP[4][32][72];     // per-wave P
    __shared__ float tbl[132];

    const int tid = threadIdx.x, wave = tid >> 6, lane = tid & 63;
    const int g = lane >> 4, c = lane & 15;
    const int bh = blockIdx.x % 48;
    const int q0 = (blockIdx.x / 48) * 128;
    const int b = bh / HH, h = bh % HH;

    if (tid < 129) tbl[tid] = rel_table[tid * HH + h] * 1.44269504f;

    bf16x8 Qh[2][2], Ql[2][2];
#pragma unroll
    for (int rt = 0; rt < 2; ++rt)
#pragma unroll
        for (int ks = 0; ks < 2; ++ks) {
            const size_t a = ((size_t)bh * NN + q0 + wave * 32 + rt * 16 + c) * 64 + ks * 32 + g * 8;
            Qh[rt][ks] = *(const bf16x8*)(qh_ + a);
            Ql[rt][ks] = *(const bf16x8*)(ql_ + a);
        }

    f32x4 O[2][4];
    float mrun[2][4], lrun[2][4];
#pragma unroll
    for (int rt = 0; rt < 2; ++rt)
#pragma unroll
        for (int r = 0; r < 4; ++r) {
            mrun[rt][r] = -INFINITY;
            lrun[rt][r] = 0.f;
        }
#pragma unroll
    for (int rt = 0; rt < 2; ++rt)
#pragma unroll
        for (int dj = 0; dj < 4; ++dj) O[rt][dj] = (f32x4)(0.f);

    __syncthreads();

    for (int t = 0; t < 16; ++t) {
        const int kv0 = t * 64;
        __syncthreads();
#pragma unroll
        for (int qq = 0; qq < 6; ++qq) {
            const int idx = wave * 6 + qq;
            if (idx < 16) {
                const int pl = idx >> 3, rem = idx & 7, jn = rem >> 1, ks = rem & 1;
                const u16* src = (pl ? kl_ : kh_) + ((size_t)bh * NN + kv0 + jn * 16 + c) * 64 + ks * 32 + g * 8;
                gld_lds16(src, &sK[pl][jn][ks][0]);
            } else {
                const int rem = idx - 16, dj = rem >> 1, ks = rem & 1;
                const u16* src = vT + ((size_t)bh << 16) + (size_t)(dj * 16 + c) * 1024 + kv0 + ks * 32 + g * 8;
                gld_lds16(src, &sV[dj][ks][0]);
            }
        }
        __syncthreads();

        f32x4 S[2][4];
#pragma unroll
        for (int rt = 0; rt < 2; ++rt)
#pragma unroll
            for (int jn = 0; jn < 4; ++jn) S[rt][jn] = (f32x4)(0.f);
        __builtin_amdgcn_s_setprio(1);
#pragma unroll
        for (int jn = 0; jn < 4; ++jn)
#pragma unroll
            for (int ks = 0; ks < 2; ++ks) {
                const bf16x8 Kh_ = *(const bf16x8*)&sK[0][jn][ks][lane * 8];
                const bf16x8 Kl_ = *(const bf16x8*)&sK[1][jn][ks][lane * 8];
#pragma unroll
                for (int rt = 0; rt < 2; ++rt) {
                    S[rt][jn] = __builtin_amdgcn_mfma_f32_16x16x32_bf16(Qh[rt][ks], Kh_, S[rt][jn], 0, 0, 0);
                    S[rt][jn] = __builtin_amdgcn_mfma_f32_16x16x32_bf16(Qh[rt][ks], Kl_, S[rt][jn], 0, 0, 0);
                    S[rt][jn] = __builtin_amdgcn_mfma_f32_16x16x32_bf16(Ql[rt][ks], Kh_, S[rt][jn], 0, 0, 0);
                }
            }
        __builtin_amdgcn_s_setprio(0);

#pragma unroll
        for (int rt = 0; rt < 2; ++rt) {
            const int R0 = q0 + wave * 32 + rt * 16;
#pragma unroll
            for (int jn = 0; jn < 4; ++jn) {
                const int dd = (kv0 + jn * 16) - R0;
                if (dd <= -79) {
                    const float bv = tbl[0];
#pragma unroll
                    for (int r = 0; r < 4; ++r) S[rt][jn][r] += bv;
                } else if (dd >= 79) {
                    const float bv = tbl[128];
#pragma unroll
                    for (int r = 0; r < 4; ++r) S[rt][jn][r] += bv;
                } else {
#pragma unroll
                    for (int r = 0; r < 4; ++r) {
                        int off = dd + c - g * 4 - r + 64;
                        off = off < 0 ? 0 : (off > 128 ? 128 : off);
                        S[rt][jn][r] += tbl[off];
                    }
                }
            }
        }

#pragma unroll
        for (int rt = 0; rt < 2; ++rt) {
#pragma unroll
            for (int r = 0; r < 4; ++r) {
                float mx = fmaxf(fmaxf(S[rt][0][r], S[rt][1][r]), fmaxf(S[rt][2][r], S[rt][3][r]));
                mx = fmaxf(mx, __shfl_xor(mx, 1));
                mx = fmaxf(mx, __shfl_xor(mx, 2));
                mx = fmaxf(mx, __shfl_xor(mx, 4));
                mx = fmaxf(mx, __shfl_xor(mx, 8));
                const float mnew = fmaxf(mrun[rt][r], mx);
                const float alpha = exp2f(mrun[rt][r] - mnew);
                mrun[rt][r] = mnew;
                float rs = 0.f;
#pragma unroll
                for (int jn = 0; jn < 4; ++jn) {
                    const float p = exp2f(S[rt][jn][r] - mnew);
                    S[rt][jn][r] = p;
                    rs += p;
                }
                rs += __shfl_xor(rs, 1);
                rs += __shfl_xor(rs, 2);
                rs += __shfl_xor(rs, 4);
                rs += __shfl_xor(rs, 8);
                lrun[rt][r] = lrun[rt][r] * alpha + rs;
#pragma unroll
                for (int dj = 0; dj < 4; ++dj) O[rt][dj][r] *= alpha;
            }
        }

#pragma unroll
        for (int rt = 0; rt < 2; ++rt)
#pragma unroll
            for (int jn = 0; jn < 4; ++jn)
#pragma unroll
                for (int r = 0; r < 4; ++r)
                    sP[wave][rt * 16 + g * 4 + r][jn * 16 + c] = bf16_rtn(S[rt][jn][r]);

        __builtin_amdgcn_s_setprio(1);
#pragma unroll
        for (int ks = 0; ks < 2; ++ks) {
            const bf16x8 Pa0 = *(const bf16x8*)&sP[wave][c][ks * 32 + g * 8];
            const bf16x8 Pa1 = *(const bf16x8*)&sP[wave][16 + c][ks * 32 + g * 8];
#pragma unroll
            for (int dj = 0; dj < 4; ++dj) {
                const bf16x8 Vf = *(const bf16x8*)&sV[dj][ks][lane * 8];
                O[0][dj] = __builtin_amdgcn_mfma_f32_16x16x32_bf16(Pa0, Vf, O[0][dj], 0, 0, 0);
                O[1][dj] = __builtin_amdgcn_mfma_f32_16x16x32_bf16(Pa1, Vf, O[1][dj], 0, 0, 0);
            }
        }
        __builtin_amdgcn_s_setprio(0);
    }

#pragma unroll
    for (int rt = 0; rt < 2; ++rt)
#pragma unroll
        for (int r = 0; r < 4; ++r) {
            const float inv = 1.0f / lrun[rt][r];
            const int n = q0 + wave * 32 + rt * 16 + g * 4 + r;
            u16* dst = attout + (size_t)(b * NN + n) * 768 + h * 64;
#pragma unroll
            for (int dj = 0; dj < 4; ++dj)
                dst[dj * 16 + c] = bf16_rtn(O[rt][dj][r] * inv);
        }
}

// ---------------------------------------------------------------------------
// Proj GEMM: attout(bf16) * proj_w^T (hi/lo) + bias -> f32.
// 64x64 tile, BK=32, 4 waves (2x2, 32x32 each), 2-phase double-buffered.
// Grid 768 blocks (3/CU), XCD-chunked swizzle.
// ---------------------------------------------------------------------------
__global__ __launch_bounds__(256) void gemm_proj(const u16* __restrict__ A,
                                                 const u16* __restrict__ Wh,
                                                 const u16* __restrict__ Wl,
                                                 const float* __restrict__ bias,
                                                 float* __restrict__ out) {
    __shared__ __align__(16) u16 sA[2][4][512];      // [buf][tile][lane*8]
    __shared__ __align__(16) u16 sB[2][2][4][512];   // [buf][pl][tile][lane*8]

    const int tid = threadIdx.x, wave = tid >> 6, lane = tid & 63;
    const int g = lane >> 4, c = lane & 15;
    // 768 = 8 XCDs x 96; m-major inside chunk
    const int bid = blockIdx.x;
    const int T = (bid & 7) * 96 + (bid >> 3);
    const int m0 = (T / 12) * 64, c0 = (T % 12) * 64;
    const int wm = wave >> 1, wn = wave & 1;

    f32x4 acc[2][2];
#pragma unroll
    for (int i = 0; i < 2; ++i)
#pragma unroll
        for (int j = 0; j < 2; ++j) acc[i][j] = (f32x4)(0.f);

    auto stage = [&](int kt, int bb) {
#pragma unroll
        for (int qq = 0; qq < 3; ++qq) {
            const int id2 = wave * 3 + qq;
            if (id2 < 4) {
                const u16* src = A + (size_t)(m0 + id2 * 16 + c) * 768 + kt * 32 + g * 8;
                gld_lds16(src, &sA[bb][id2][0]);
            } else {
                const int rem = id2 - 4, pl = rem >> 2, t = rem & 3;
                const u16* src = (pl ? Wl : Wh) + (size_t)(c0 + t * 16 + c) * 768 + kt * 32 + g * 8;
                gld_lds16(src, &sB[bb][pl][t][0]);
            }
        }
    };

    stage(0, 0);
    for (int kt = 0; kt < 24; ++kt) {
        const int bb = kt & 1;
        __syncthreads();
        if (kt < 23) stage(kt + 1, bb ^ 1);

        bf16x8 Aa[2], Bh[2], Bl[2];
#pragma unroll
        for (int i = 0; i < 2; ++i) {
            Aa[i] = *(const bf16x8*)&sA[bb][wm * 2 + i][lane * 8];
            Bh[i] = *(const bf16x8*)&sB[bb][0][wn * 2 + i][lane * 8];
            Bl[i] = *(const bf16x8*)&sB[bb][1][wn * 2 + i][lane * 8];
        }
#pragma unroll
        for (int i = 0; i < 2; ++i)
#pragma unroll
            for (int j = 0; j < 2; ++j) {
                acc[i][j] = __builtin_amdgcn_mfma_f32_16x16x32_bf16(Aa[i], Bh[j], acc[i][j], 0, 0, 0);
                acc[i][j] = __builtin_amdgcn_mfma_f32_16x16x32_bf16(Aa[i], Bl[j], acc[i][j], 0, 0, 0);
            }
    }

#pragma unroll
    for (int j = 0; j < 2; ++j) {
        const int cg = c0 + wn * 32 + j * 16 + c;
        const float bv = bias[cg];
#pragma unroll
        for (int i = 0; i < 2; ++i)
#pragma unroll
            for (int r = 0; r < 4; ++r) {
                const int m = m0 + wm * 32 + i * 16 + g * 4 + r;
                out[(size_t)m * 768 + cg] = acc[i][j][r] + bv;
            }
    }
}

// ---------------------------------------------------------------------------
extern "C" void kernel_launch(void* const* d_in, const int* in_sizes, int n_in,
                              void* d_out, int out_size, void* d_ws, size_t ws_size,
                              hipStream_t stream) {
    const float* x = (const float*)d_in[0];
    const float* qkv_w = (const float*)d_in[1];
    const float* proj_w = (const float*)d_in[2];
    const float* proj_b = (const float*)d_in[3];
    const float* rel_table = (const float*)d_in[4];

    char* ws = (char*)d_ws;
    // Layout (peak 48.75 MB) with lifetime-based aliasing:
    u16* qkvwh = (u16*)(ws);                  // 3,538,944   [presplit .. gemm_qkv]
    u16* qkvwl = (u16*)(ws + 3538944);        // 3,538,944
    u16* xh    = (u16*)(ws + 7077888);        // 6,291,456   [presplit .. gemm_qkv]
    u16* xl    = (u16*)(ws + 13369344);       // 6,291,456
    u16* qh    = (u16*)(ws + 19660800);       // 6,291,456
    u16* ql    = (u16*)(ws + 25952256);
    u16* kh    = (u16*)(ws + 32243712);
    u16* kl    = (u16*)(ws + 38535168);
    u16* vT    = (u16*)(ws + 44826624);       // -> 51,118,080
    u16* ao    = (u16*)(ws + 7077888);        // aliases xh (dead after gemm_qkv)
    u16* pwh   = (u16*)(ws + 13369344);       // aliases xl (split after gemm_qkv)
    u16* pwl   = (u16*)(ws + 14548992);

    // 1) presplit x and qkv_w   (x: 4096*768 floats = 786,432 float4)
    presplit<<<dim3(3072), 256, 0, stream>>>(x, xh, xl, 786432);
    presplit<<<dim3(1728), 256, 0, stream>>>(qkv_w, qkvwh, qkvwl, 442368);

    // 2) QKV projection (2-phase pipelined, all-async staging)
    gemm_qkv<<<dim3(576), 256, 0, stream>>>(xh, xl, qkvwh, qkvwl, qh, ql, kh, kl, vT);

    // 3) presplit proj_w (into xl's region, now dead)
    presplit<<<dim3(576), 256, 0, stream>>>(proj_w, pwh, pwl, 147456);

    // 4) attention -> attout bf16 (aliases xh region)
    attn_mfma<<<dim3(384), 256, 0, stream>>>(qh, ql, kh, kl, vT, rel_table, ao);

    // 5) output projection + bias -> f32
    gemm_proj<<<dim3(768), 256, 0, stream>>>(ao, pwh, pwl, proj_b, (float*)d_out);
}

// Round 7
// 310.271 us; speedup vs baseline: 1.2421x; 1.2421x over previous
//
#include <hip/hip_runtime.h>
#include <math.h>

#define HH 12
#define NN 1024

typedef unsigned int u32;
typedef unsigned short u16;
typedef __attribute__((ext_vector_type(8))) short bf16x8;
typedef __attribute__((ext_vector_type(4))) float f32x4;
typedef __attribute__((ext_vector_type(4))) unsigned short u16x4;

#define QSCALE 0.18033688f   // 0.125 * log2(e): folded scale + base-2 softmax

__device__ __forceinline__ u16 bf16_rtn(float f) {
    u32 u = __builtin_bit_cast(u32, f);
    return (u16)((u + 0x7FFFu + ((u >> 16) & 1u)) >> 16);
}
__device__ __forceinline__ float bf16_up(u16 h) {
    u32 u = ((u32)h) << 16;
    return __builtin_bit_cast(float, u);
}
// async global->LDS, 16B per lane, dest = uniform base + lane*16
__device__ __forceinline__ void gld_lds16(const void* g, void* l) {
    __builtin_amdgcn_global_load_lds(
        (const __attribute__((address_space(1))) u32*)(unsigned long long)g,
        (__attribute__((address_space(3))) u32*)(u32)(unsigned long long)l,
        16, 0, 0);
}

// ---------------------------------------------------------------------------
// One-time f32 -> (hi,lo) bf16 split, rtn both planes (err ~2^-18)
// ---------------------------------------------------------------------------
__global__ __launch_bounds__(256) void presplit(const float* __restrict__ in,
                                                u16* __restrict__ hi, u16* __restrict__ lo,
                                                int n4) {
    int i = blockIdx.x * 256 + threadIdx.x;
    if (i >= n4) return;
    float4 v = ((const float4*)in)[i];
    float f[4] = {v.x, v.y, v.z, v.w};
    u16x4 h, l;
#pragma unroll
    for (int j = 0; j < 4; ++j) {
        u16 hh = bf16_rtn(f[j]);
        h[j] = hh;
        l[j] = bf16_rtn(f[j] - bf16_up(hh));
    }
    ((u16x4*)hi)[i] = h;
    ((u16x4*)lo)[i] = l;
}

// ---------------------------------------------------------------------------
// QKV GEMM: Xsplit(4096x768 bf16 hi/lo) * qkv_w^T (bf16 hi/lo).
// 128x64 tile, BK=32, 4 waves 2x2 (wave = 64x32), 3-term split MFMA.
// m97 structure: SINGLE-buffer LDS (24KB), stage->barrier->compute->barrier,
// all staging via global_load_lds. Grid 1152 = 4.5 blocks/CU for TLP.
// XCD-chunked swizzle (m-major within chunk).
// ---------------------------------------------------------------------------
__global__ __launch_bounds__(256) void gemm_qkv(const u16* __restrict__ Xh,
                                                const u16* __restrict__ Xl,
                                                const u16* __restrict__ Wh,
                                                const u16* __restrict__ Wl,
                                                u16* __restrict__ qh, u16* __restrict__ ql,
                                                u16* __restrict__ kh, u16* __restrict__ kl,
                                                u16* __restrict__ vT) {
    __shared__ __align__(16) u16 sA[2][8][512];   // [pl][tile][lane*8] 16KB
    __shared__ __align__(16) u16 sB[2][4][512];   // [pl][tile][lane*8]  8KB

    const int tid = threadIdx.x, wave = tid >> 6, lane = tid & 63;
    const int g = lane >> 4, c = lane & 15;
    // 1152 blocks = 8 XCDs x 144; m-major inside chunk (4 m-panels x 36 c)
    const int bid = blockIdx.x;
    const int T = (bid & 7) * 144 + (bid >> 3);
    const int m0 = (T / 36) * 128, c0 = (T % 36) * 64;
    const int wm = wave >> 1, wn = wave & 1;

    f32x4 acc[4][2];
#pragma unroll
    for (int i = 0; i < 4; ++i)
#pragma unroll
        for (int j = 0; j < 2; ++j) acc[i][j] = (f32x4)(0.f);

    for (int kt = 0; kt < 24; ++kt) {
        __syncthreads();   // prev iter's frag reads done
        // 24 chunks: A 16 (8 tiles x hi/lo), B 8 (4 tiles x hi/lo); 6 per wave
#pragma unroll
        for (int qq = 0; qq < 6; ++qq) {
            const int idx = wave * 6 + qq;
            if (idx < 16) {
                const int pl = idx >> 3, t = idx & 7;
                const u16* src = (pl ? Xl : Xh) + (size_t)(m0 + t * 16 + c) * 768 + kt * 32 + g * 8;
                gld_lds16(src, &sA[pl][t][0]);
            } else {
                const int rem = idx - 16, pl = rem >> 2, t = rem & 3;
                const u16* src = (pl ? Wl : Wh) + (size_t)(c0 + t * 16 + c) * 768 + kt * 32 + g * 8;
                gld_lds16(src, &sB[pl][t][0]);
            }
        }
        __syncthreads();   // staging visible

        bf16x8 Ah[4], Al[4], Bh[2], Bl[2];
#pragma unroll
        for (int i = 0; i < 4; ++i) {
            Ah[i] = *(const bf16x8*)&sA[0][wm * 4 + i][lane * 8];
            Al[i] = *(const bf16x8*)&sA[1][wm * 4 + i][lane * 8];
        }
#pragma unroll
        for (int j = 0; j < 2; ++j) {
            Bh[j] = *(const bf16x8*)&sB[0][wn * 2 + j][lane * 8];
            Bl[j] = *(const bf16x8*)&sB[1][wn * 2 + j][lane * 8];
        }
#pragma unroll
        for (int i = 0; i < 4; ++i)
#pragma unroll
            for (int j = 0; j < 2; ++j) {
                acc[i][j] = __builtin_amdgcn_mfma_f32_16x16x32_bf16(Ah[i], Bh[j], acc[i][j], 0, 0, 0);
                acc[i][j] = __builtin_amdgcn_mfma_f32_16x16x32_bf16(Ah[i], Bl[j], acc[i][j], 0, 0, 0);
                acc[i][j] = __builtin_amdgcn_mfma_f32_16x16x32_bf16(Al[i], Bh[j], acc[i][j], 0, 0, 0);
            }
    }

    // Epilogue: D-frag row = g*4+r, col = c (HW-verified)
    const int b = m0 >> 10;
#pragma unroll
    for (int j = 0; j < 2; ++j) {
        const int cg = c0 + wn * 32 + j * 16;
        const int s = cg / 768;
        const int h = (cg % 768) / 64;
        const int d = (cg % 64) + c;
#pragma unroll
        for (int i = 0; i < 4; ++i) {
            const int nbase = (m0 & 1023) + wm * 64 + i * 16 + g * 4;
            if (s == 2) {
                u16x4 pk;
#pragma unroll
                for (int r = 0; r < 4; ++r) pk[r] = bf16_rtn(acc[i][j][r]);
                *(u16x4*)(vT + ((size_t)(b * HH + h) << 16) + (size_t)d * 1024 + nbase) = pk;
            } else {
                u16* dh = s ? kh : qh;
                u16* dl = s ? kl : ql;
                const float sc = s ? 1.0f : QSCALE;
#pragma unroll
                for (int r = 0; r < 4; ++r) {
                    const float vv = acc[i][j][r] * sc;
                    const u16 hh = bf16_rtn(vv);
                    const size_t a = ((size_t)(b * HH + h) * NN + nbase + r) * 64 + d;
                    dh[a] = hh;
                    dl[a] = bf16_rtn(vv - bf16_up(hh));
                }
            }
        }
    }
}

// ---------------------------------------------------------------------------
// Flash attention, MFMA, NO K/V staging, NO per-tile barriers.
// K/V are L2-resident (384 KB per bh); fragments loaded directly from global
// at the same per-lane addresses the staged path used. Waves free-run:
// next-tile loads overlap current-tile softmax/PV (no barrier blocks them).
// LDS: per-wave P transpose buffer + bias table only.
// ---------------------------------------------------------------------------
__global__ __launch_bounds__(256) void attn_mfma(const u16* __restrict__ qh_,
                                                 const u16* __restrict__ ql_,
                                                 const u16* __restrict__ kh_,
                                                 const u16* __restrict__ kl_,
                                                 const u16* __restrict__ vT,
                                                 const float* __restrict__ rel_table,
                                                 u16* __restrict__ attout) {
    __shared__ __align__(16) u16 sP[4][32][72];     // per-wave P (18KB)
    __shared__ float tbl[132];

    const int tid = threadIdx.x, wave = tid >> 6, lane = tid & 63;
    const int g = lane >> 4, c = lane & 15;
    const int bh = blockIdx.x % 48;
    const int q0 = (blockIdx.x / 48) * 128;
    const int b = bh / HH, h = bh % HH;

    if (tid < 129) tbl[tid] = rel_table[tid * HH + h] * 1.44269504f;

    // hoist Q fragments (rows q0+wave*32 .. +32)
    bf16x8 Qh[2][2], Ql[2][2];
#pragma unroll
    for (int rt = 0; rt < 2; ++rt)
#pragma unroll
        for (int ks = 0; ks < 2; ++ks) {
            const size_t a = ((size_t)bh * NN + q0 + wave * 32 + rt * 16 + c) * 64 + ks * 32 + g * 8;
            Qh[rt][ks] = *(const bf16x8*)(qh_ + a);
            Ql[rt][ks] = *(const bf16x8*)(ql_ + a);
        }

    // lane-fixed base pointers for direct K/V fragment loads
    const u16* kbh = kh_ + ((size_t)bh * NN + c) * 64 + g * 8;
    const u16* kbl = kl_ + ((size_t)bh * NN + c) * 64 + g * 8;
    const u16* vb = vT + ((size_t)bh << 16) + (size_t)c * 1024 + g * 8;

    f32x4 O[2][4];
    float mrun[2][4], lrun[2][4];
#pragma unroll
    for (int rt = 0; rt < 2; ++rt)
#pragma unroll
        for (int r = 0; r < 4; ++r) {
            mrun[rt][r] = -INFINITY;
            lrun[rt][r] = 0.f;
        }
#pragma unroll
    for (int rt = 0; rt < 2; ++rt)
#pragma unroll
        for (int dj = 0; dj < 4; ++dj) O[rt][dj] = (f32x4)(0.f);

    __syncthreads();  // tbl visible (only barrier in the kernel)

    for (int t = 0; t < 16; ++t) {
        const int kv0 = t * 64;

        // S = QK^T (3-term split), K fragments direct from global (L2)
        f32x4 S[2][4];
#pragma unroll
        for (int rt = 0; rt < 2; ++rt)
#pragma unroll
            for (int jn = 0; jn < 4; ++jn) S[rt][jn] = (f32x4)(0.f);
#pragma unroll
        for (int jn = 0; jn < 4; ++jn) {
#pragma unroll
            for (int ks = 0; ks < 2; ++ks) {
                const size_t off = (size_t)(kv0 + jn * 16) * 64 + ks * 32;
                const bf16x8 Kh_ = *(const bf16x8*)(kbh + off);
                const bf16x8 Kl_ = *(const bf16x8*)(kbl + off);
                __builtin_amdgcn_s_setprio(1);
#pragma unroll
                for (int rt = 0; rt < 2; ++rt) {
                    S[rt][jn] = __builtin_amdgcn_mfma_f32_16x16x32_bf16(Qh[rt][ks], Kh_, S[rt][jn], 0, 0, 0);
                    S[rt][jn] = __builtin_amdgcn_mfma_f32_16x16x32_bf16(Qh[rt][ks], Kl_, S[rt][jn], 0, 0, 0);
                    S[rt][jn] = __builtin_amdgcn_mfma_f32_16x16x32_bf16(Ql[rt][ks], Kh_, S[rt][jn], 0, 0, 0);
                }
                __builtin_amdgcn_s_setprio(0);
            }
        }

        // + relative-position bias (log2 domain); wave-uniform clamp fast path
#pragma unroll
        for (int rt = 0; rt < 2; ++rt) {
            const int R0 = q0 + wave * 32 + rt * 16;
#pragma unroll
            for (int jn = 0; jn < 4; ++jn) {
                const int dd = (kv0 + jn * 16) - R0;
                if (dd <= -79) {
                    const float bv = tbl[0];
#pragma unroll
                    for (int r = 0; r < 4; ++r) S[rt][jn][r] += bv;
                } else if (dd >= 79) {
                    const float bv = tbl[128];
#pragma unroll
                    for (int r = 0; r < 4; ++r) S[rt][jn][r] += bv;
                } else {
#pragma unroll
                    for (int r = 0; r < 4; ++r) {
                        int off = dd + c - g * 4 - r + 64;
                        off = off < 0 ? 0 : (off > 128 ? 128 : off);
                        S[rt][jn][r] += tbl[off];
                    }
                }
            }
        }

        // online softmax (base 2); rows live on 16-lane c-groups
#pragma unroll
        for (int rt = 0; rt < 2; ++rt) {
#pragma unroll
            for (int r = 0; r < 4; ++r) {
                float mx = fmaxf(fmaxf(S[rt][0][r], S[rt][1][r]), fmaxf(S[rt][2][r], S[rt][3][r]));
                mx = fmaxf(mx, __shfl_xor(mx, 1));
                mx = fmaxf(mx, __shfl_xor(mx, 2));
                mx = fmaxf(mx, __shfl_xor(mx, 4));
                mx = fmaxf(mx, __shfl_xor(mx, 8));
                const float mnew = fmaxf(mrun[rt][r], mx);
                const float alpha = exp2f(mrun[rt][r] - mnew);
                mrun[rt][r] = mnew;
                float rs = 0.f;
#pragma unroll
                for (int jn = 0; jn < 4; ++jn) {
                    const float p = exp2f(S[rt][jn][r] - mnew);
                    S[rt][jn][r] = p;
                    rs += p;
                }
                rs += __shfl_xor(rs, 1);
                rs += __shfl_xor(rs, 2);
                rs += __shfl_xor(rs, 4);
                rs += __shfl_xor(rs, 8);
                lrun[rt][r] = lrun[rt][r] * alpha + rs;
#pragma unroll
                for (int dj = 0; dj < 4; ++dj) O[rt][dj][r] *= alpha;
            }
        }

        // P -> bf16, transpose through per-wave LDS (wave-coherent, no barrier)
#pragma unroll
        for (int rt = 0; rt < 2; ++rt)
#pragma unroll
            for (int jn = 0; jn < 4; ++jn)
#pragma unroll
                for (int r = 0; r < 4; ++r)
                    sP[wave][rt * 16 + g * 4 + r][jn * 16 + c] = bf16_rtn(S[rt][jn][r]);

        // O += P V, V fragments direct from global (L2)
#pragma unroll
        for (int ks = 0; ks < 2; ++ks) {
            const bf16x8 Pa0 = *(const bf16x8*)&sP[wave][c][ks * 32 + g * 8];
            const bf16x8 Pa1 = *(const bf16x8*)&sP[wave][16 + c][ks * 32 + g * 8];
#pragma unroll
            for (int dj = 0; dj < 4; ++dj) {
                const bf16x8 Vf = *(const bf16x8*)(vb + (size_t)(dj * 16) * 1024 + kv0 + ks * 32);
                __builtin_amdgcn_s_setprio(1);
                O[0][dj] = __builtin_amdgcn_mfma_f32_16x16x32_bf16(Pa0, Vf, O[0][dj], 0, 0, 0);
                O[1][dj] = __builtin_amdgcn_mfma_f32_16x16x32_bf16(Pa1, Vf, O[1][dj], 0, 0, 0);
                __builtin_amdgcn_s_setprio(0);
            }
        }
    }

    // epilogue: normalize, write attout bf16 [b][n][768]
#pragma unroll
    for (int rt = 0; rt < 2; ++rt)
#pragma unroll
        for (int r = 0; r < 4; ++r) {
            const float inv = 1.0f / lrun[rt][r];
            const int n = q0 + wave * 32 + rt * 16 + g * 4 + r;
            u16* dst = attout + (size_t)(b * NN + n) * 768 + h * 64;
#pragma unroll
            for (int dj = 0; dj < 4; ++dj)
                dst[dj * 16 + c] = bf16_rtn(O[rt][dj][r] * inv);
        }
}

// ---------------------------------------------------------------------------
// Proj GEMM: attout(bf16) * proj_w^T (hi/lo) + bias -> f32.
// 64x64 tile, BK=32, 4 waves 2x2 (wave 32x32), SINGLE-buffer (12KB),
// 2 barriers/iter, async staging. Grid 768 (3 blocks/CU), XCD-chunked.
// ---------------------------------------------------------------------------
__global__ __launch_bounds__(256) void gemm_proj(const u16* __restrict__ A,
                                                 const u16* __restrict__ Wh,
                                                 const u16* __restrict__ Wl,
                                                 const float* __restrict__ bias,
                                                 float* __restrict__ out) {
    __shared__ __align__(16) u16 sA[4][512];      // [tile][lane*8]  4KB
    __shared__ __align__(16) u16 sB[2][4][512];   // [pl][tile][lane*8] 8KB

    const int tid = threadIdx.x, wave = tid >> 6, lane = tid & 63;
    const int g = lane >> 4, c = lane & 15;
    // 768 = 8 XCDs x 96; m-major inside chunk
    const int bid = blockIdx.x;
    const int T = (bid & 7) * 96 + (bid >> 3);
    const int m0 = (T / 12) * 64, c0 = (T % 12) * 64;
    const int wm = wave >> 1, wn = wave & 1;

    f32x4 acc[2][2];
#pragma unroll
    for (int i = 0; i < 2; ++i)
#pragma unroll
        for (int j = 0; j < 2; ++j) acc[i][j] = (f32x4)(0.f);

    for (int kt = 0; kt < 24; ++kt) {
        __syncthreads();
#pragma unroll
        for (int qq = 0; qq < 3; ++qq) {
            const int idx = wave * 3 + qq;
            if (idx < 4) {
                const u16* src = A + (size_t)(m0 + idx * 16 + c) * 768 + kt * 32 + g * 8;
                gld_lds16(src, &sA[idx][0]);
            } else {
                const int rem = idx - 4, pl = rem >> 2, t = rem & 3;
                const u16* src = (pl ? Wl : Wh) + (size_t)(c0 + t * 16 + c) * 768 + kt * 32 + g * 8;
                gld_lds16(src, &sB[pl][t][0]);
            }
        }
        __syncthreads();

        bf16x8 Aa[2], Bh[2], Bl[2];
#pragma unroll
        for (int i = 0; i < 2; ++i) {
            Aa[i] = *(const bf16x8*)&sA[wm * 2 + i][lane * 8];
            Bh[i] = *(const bf16x8*)&sB[0][wn * 2 + i][lane * 8];
            Bl[i] = *(const bf16x8*)&sB[1][wn * 2 + i][lane * 8];
        }
#pragma unroll
        for (int i = 0; i < 2; ++i)
#pragma unroll
            for (int j = 0; j < 2; ++j) {
                acc[i][j] = __builtin_amdgcn_mfma_f32_16x16x32_bf16(Aa[i], Bh[j], acc[i][j], 0, 0, 0);
                acc[i][j] = __builtin_amdgcn_mfma_f32_16x16x32_bf16(Aa[i], Bl[j], acc[i][j], 0, 0, 0);
            }
    }

#pragma unroll
    for (int j = 0; j < 2; ++j) {
        const int cg = c0 + wn * 32 + j * 16 + c;
        const float bv = bias[cg];
#pragma unroll
        for (int i = 0; i < 2; ++i)
#pragma unroll
            for (int r = 0; r < 4; ++r) {
                const int m = m0 + wm * 32 + i * 16 + g * 4 + r;
                out[(size_t)m * 768 + cg] = acc[i][j][r] + bv;
            }
    }
}

// ---------------------------------------------------------------------------
extern "C" void kernel_launch(void* const* d_in, const int* in_sizes, int n_in,
                              void* d_out, int out_size, void* d_ws, size_t ws_size,
                              hipStream_t stream) {
    const float* x = (const float*)d_in[0];
    const float* qkv_w = (const float*)d_in[1];
    const float* proj_w = (const float*)d_in[2];
    const float* proj_b = (const float*)d_in[3];
    const float* rel_table = (const float*)d_in[4];

    char* ws = (char*)d_ws;
    // Layout (peak 48.75 MB) with lifetime-based aliasing:
    u16* qkvwh = (u16*)(ws);                  // 3,538,944   [presplit .. gemm_qkv]
    u16* qkvwl = (u16*)(ws + 3538944);        // 3,538,944
    u16* xh    = (u16*)(ws + 7077888);        // 6,291,456   [presplit .. gemm_qkv]
    u16* xl    = (u16*)(ws + 13369344);       // 6,291,456
    u16* qh    = (u16*)(ws + 19660800);       // 6,291,456
    u16* ql    = (u16*)(ws + 25952256);
    u16* kh    = (u16*)(ws + 32243712);
    u16* kl    = (u16*)(ws + 38535168);
    u16* vT    = (u16*)(ws + 44826624);       // -> 51,118,080
    u16* ao    = (u16*)(ws + 7077888);        // aliases xh (dead after gemm_qkv)
    u16* pwh   = (u16*)(ws + 13369344);       // aliases xl (split after gemm_qkv)
    u16* pwl   = (u16*)(ws + 14548992);

    // 1) presplit x and qkv_w   (x: 4096*768 floats = 786,432 float4)
    presplit<<<dim3(3072), 256, 0, stream>>>(x, xh, xl, 786432);
    presplit<<<dim3(1728), 256, 0, stream>>>(qkv_w, qkvwh, qkvwl, 442368);

    // 2) QKV projection (single-buffer m97 structure, 128x64 tiles, 1152 blocks)
    gemm_qkv<<<dim3(1152), 256, 0, stream>>>(xh, xl, qkvwh, qkvwl, qh, ql, kh, kl, vT);

    // 3) presplit proj_w (into xl's region, now dead)
    presplit<<<dim3(576), 256, 0, stream>>>(proj_w, pwh, pwl, 147456);

    // 4) attention -> attout bf16 (barrier-free main loop, direct K/V loads)
    attn_mfma<<<dim3(384), 256, 0, stream>>>(qh, ql, kh, kl, vT, rel_table, ao);

    // 5) output projection + bias -> f32 (single-buffer, 768 blocks)
    gemm_proj<<<dim3(768), 256, 0, stream>>>(ao, pwh, pwl, proj_b, (float*)d_out);
}